// Round 2
// baseline (590.115 us; speedup 1.0000x reference)
//
#include <hip/hip_runtime.h>
#include <hip/hip_bf16.h>

#define DIM 256
#define NP 2048
#define NH 8
#define BATCH 2
#define DH 32
#define RPB 8

__device__ __forceinline__ float bflo(unsigned int u) {
    union { unsigned int i; float f; } a; a.i = u << 16; return a.f;
}
__device__ __forceinline__ float bfhi(unsigned int u) {
    union { unsigned int i; float f; } a; a.i = u & 0xffff0000u; return a.f;
}

// ---------------- kernel 1: fused QKV projection (fp32 in -> bf16 q/k/v) ----
// x[B*N, 256] @ Wqk[256,512] and @ Wv[256,256] -> q,k,v in [B,H,N,DH] bf16
__global__ __launch_bounds__(256) void qkv_kernel(
    const float* __restrict__ x,
    const float* __restrict__ Wqk,
    const float* __restrict__ Wv,
    __hip_bfloat16* __restrict__ q,
    __hip_bfloat16* __restrict__ k,
    __hip_bfloat16* __restrict__ v) {
    __shared__ float xs[RPB][DIM];
    const int t = threadIdx.x;
    const int row0 = blockIdx.x * RPB;

#pragma unroll
    for (int j = 0; j < RPB; j++)
        xs[j][t] = x[(size_t)(row0 + j) * DIM + t];
    __syncthreads();

    float aq[RPB], ak[RPB], av[RPB];
#pragma unroll
    for (int j = 0; j < RPB; j++) { aq[j] = 0.f; ak[j] = 0.f; av[j] = 0.f; }

    for (int i = 0; i < DIM; i++) {
        float wq = Wqk[i * 512 + t];
        float wk = Wqk[i * 512 + 256 + t];
        float wv = Wv[i * 256 + t];
#pragma unroll
        for (int j = 0; j < RPB; j++) {
            float xv = xs[j][i];
            aq[j] = fmaf(xv, wq, aq[j]);
            ak[j] = fmaf(xv, wk, ak[j]);
            av[j] = fmaf(xv, wv, av[j]);
        }
    }

    const int h = t >> 5, d = t & 31;
#pragma unroll
    for (int j = 0; j < RPB; j++) {
        int row = row0 + j;
        int b = row >> 11, n = row & (NP - 1);
        size_t o = ((size_t)(b * NH + h) * NP + n) * DH + d;
        q[o] = __float2bfloat16(aq[j]);
        k[o] = __float2bfloat16(ak[j]);
        v[o] = __float2bfloat16(av[j]);
    }
}

// ---------------- kernel 2: gated positional attention ----------------
// one block per (b,h,n) query row; q/k/v bf16, scalars fp32
__global__ __launch_bounds__(256) void attn_kernel(
    const __hip_bfloat16* __restrict__ qg,
    const __hip_bfloat16* __restrict__ kg,
    const __hip_bfloat16* __restrict__ vg,
    const float* __restrict__ Wpos,
    const float* __restrict__ bpos,
    const float* __restrict__ gating,
    float* __restrict__ attn_out) {
    __shared__ float sw[NP];   // content scores -> exp -> combined weights
    __shared__ float sp[NP];   // positional raw -> exp ; reused as reduce scratch
    __shared__ float redA[4], redB[4];

    const int t = threadIdx.x;
    const int idx = blockIdx.x;            // (b*NH + h)*NP + n
    const int n = idx & (NP - 1);
    const int bh = idx >> 11;
    const int h = bh & (NH - 1);
    const int b = bh >> 3;

    const __hip_bfloat16* qrow = qg + (size_t)idx * DH;
    const __hip_bfloat16* kb = kg + (size_t)bh * NP * DH;
    const __hip_bfloat16* vb = vg + (size_t)bh * NP * DH;

    // q row -> registers (broadcast load, 64B)
    float qreg[DH];
    {
        const uint4* qr4 = (const uint4*)qrow;
#pragma unroll
        for (int j = 0; j < 4; j++) {
            uint4 u = qr4[j];
            qreg[8 * j + 0] = bflo(u.x); qreg[8 * j + 1] = bfhi(u.x);
            qreg[8 * j + 2] = bflo(u.y); qreg[8 * j + 3] = bfhi(u.y);
            qreg[8 * j + 4] = bflo(u.z); qreg[8 * j + 5] = bfhi(u.z);
            qreg[8 * j + 6] = bflo(u.w); qreg[8 * j + 7] = bfhi(u.w);
        }
    }

    const float w0 = Wpos[h];
    const float w1 = Wpos[NH + h];
    const float bp = bpos[h];
    const float gate = gating[h];
    const float g = 1.0f / (1.0f + __expf(-gate));
    const float scale = 0.17677669529663687f;  // 32^-0.5

    // pass 1: scores + positional raw, track maxes
    float smax = -3.0e38f, pmax = -3.0e38f;
    for (int m = t; m < NP; m += 256) {
        const uint4* kr = (const uint4*)(kb + (size_t)m * DH);
        float acc = 0.f;
#pragma unroll
        for (int j = 0; j < 4; j++) {
            uint4 u = kr[j];
            acc = fmaf(qreg[8 * j + 0], bflo(u.x), acc);
            acc = fmaf(qreg[8 * j + 1], bfhi(u.x), acc);
            acc = fmaf(qreg[8 * j + 2], bflo(u.y), acc);
            acc = fmaf(qreg[8 * j + 3], bfhi(u.y), acc);
            acc = fmaf(qreg[8 * j + 4], bflo(u.z), acc);
            acc = fmaf(qreg[8 * j + 5], bfhi(u.z), acc);
            acc = fmaf(qreg[8 * j + 6], bflo(u.w), acc);
            acc = fmaf(qreg[8 * j + 7], bfhi(u.w), acc);
        }
        acc *= scale;
        sw[m] = acc;
        smax = fmaxf(smax, acc);
        float dd = (float)(n - m);
        float p = fmaf(w0, dd, fmaf(w1, fabsf(dd), bp));
        sp[m] = p;
        pmax = fmaxf(pmax, p);
    }

    // block-reduce maxes
#pragma unroll
    for (int off = 32; off; off >>= 1) {
        smax = fmaxf(smax, __shfl_xor(smax, off, 64));
        pmax = fmaxf(pmax, __shfl_xor(pmax, off, 64));
    }
    const int wid = t >> 6, lane = t & 63;
    if (lane == 0) { redA[wid] = smax; redB[wid] = pmax; }
    __syncthreads();
    smax = fmaxf(fmaxf(redA[0], redA[1]), fmaxf(redA[2], redA[3]));
    pmax = fmaxf(fmaxf(redB[0], redB[1]), fmaxf(redB[2], redB[3]));
    __syncthreads();  // redA/redB reused below

    // pass 2: exponentials + sums
    float ssum = 0.f, psum = 0.f;
    for (int m = t; m < NP; m += 256) {
        float es = __expf(sw[m] - smax);
        float ep = __expf(sp[m] - pmax);
        sw[m] = es; sp[m] = ep;
        ssum += es; psum += ep;
    }
#pragma unroll
    for (int off = 32; off; off >>= 1) {
        ssum += __shfl_xor(ssum, off, 64);
        psum += __shfl_xor(psum, off, 64);
    }
    if (lane == 0) { redA[wid] = ssum; redB[wid] = psum; }
    __syncthreads();
    ssum = redA[0] + redA[1] + redA[2] + redA[3];
    psum = redB[0] + redB[1] + redB[2] + redB[3];

    const float ca = (1.0f - g) / ssum;
    const float cb = g / psum;

    // combine weights (each thread owns its own m's)
    for (int m = t; m < NP; m += 256)
        sw[m] = fmaf(ca, sw[m], cb * sp[m]);
    __syncthreads();  // sw now complete; sp free for reuse

    // AV pass: thread t handles d-quad dq = t&7 (d = dq*4..+3), m-group mg = t>>3
    const int dq = t & 7, mg = t >> 3;
    float a0 = 0.f, a1 = 0.f, a2 = 0.f, a3 = 0.f;
    for (int m = mg; m < NP; m += 32) {
        float wgt = sw[m];
        uint2 u = *(const uint2*)(vb + (size_t)m * DH + dq * 4);
        a0 = fmaf(wgt, bflo(u.x), a0);
        a1 = fmaf(wgt, bfhi(u.x), a1);
        a2 = fmaf(wgt, bflo(u.y), a2);
        a3 = fmaf(wgt, bfhi(u.y), a3);
    }
    // partials -> sp (as 256 float4), reduce 32 m-groups
    float4* racc = (float4*)sp;
    racc[t] = make_float4(a0, a1, a2, a3);
    __syncthreads();
    if (t < 32) {
        // output channel d = t: quad = t>>2, comp = t&3
        float r = 0.f;
#pragma unroll
        for (int mgj = 0; mgj < 32; mgj++)
            r += sp[(mgj * 8 + (t >> 2)) * 4 + (t & 3)];
        attn_out[((size_t)(b * NP + n)) * DIM + h * DH + t] = r;
    }
}

// ---------------- kernel 3: output projection + bias (fp32) ----------------
__global__ __launch_bounds__(256) void proj_kernel(
    const float* __restrict__ a,
    const float* __restrict__ W,
    const float* __restrict__ bias,
    float* __restrict__ out) {
    __shared__ float xs[RPB][DIM];
    const int t = threadIdx.x;
    const int row0 = blockIdx.x * RPB;

#pragma unroll
    for (int j = 0; j < RPB; j++)
        xs[j][t] = a[(size_t)(row0 + j) * DIM + t];
    __syncthreads();

    float acc[RPB];
    float bb = bias[t];
#pragma unroll
    for (int j = 0; j < RPB; j++) acc[j] = bb;

    for (int i = 0; i < DIM; i++) {
        float wv = W[i * DIM + t];
#pragma unroll
        for (int j = 0; j < RPB; j++)
            acc[j] = fmaf(xs[j][i], wv, acc[j]);
    }

#pragma unroll
    for (int j = 0; j < RPB; j++)
        out[(size_t)(row0 + j) * DIM + t] = acc[j];
}

extern "C" void kernel_launch(void* const* d_in, const int* in_sizes, int n_in,
                              void* d_out, int out_size, void* d_ws, size_t ws_size,
                              hipStream_t stream) {
    const float* x      = (const float*)d_in[0];
    const float* Wqk    = (const float*)d_in[1];
    const float* Wv     = (const float*)d_in[2];
    const float* Wproj  = (const float*)d_in[3];
    const float* bproj  = (const float*)d_in[4];
    const float* Wpos   = (const float*)d_in[5];
    const float* bpos   = (const float*)d_in[6];
    const float* gating = (const float*)d_in[7];
    float* out = (float*)d_out;

    const size_t nElem = (size_t)BATCH * NH * NP * DH;  // 1,048,576
    char* w = (char*)d_ws;
    __hip_bfloat16* q = (__hip_bfloat16*)w;
    __hip_bfloat16* k = q + nElem;
    __hip_bfloat16* v = k + nElem;
    float* attn_out = (float*)(w + 3 * nElem * sizeof(__hip_bfloat16));  // +6 MB

    qkv_kernel<<<BATCH * NP / RPB, 256, 0, stream>>>(x, Wqk, Wv, q, k, v);
    attn_kernel<<<BATCH * NH * NP, 256, 0, stream>>>(q, k, v, Wpos, bpos, gating, attn_out);
    proj_kernel<<<BATCH * NP / RPB, 256, 0, stream>>>(attn_out, Wproj, bproj, out);
}

// Round 3
// 174.726 us; speedup vs baseline: 3.3774x; 3.3774x over previous
//
#include <hip/hip_runtime.h>
#include <hip/hip_bf16.h>

#define DIM 256
#define NP 2048
#define NH 8
#define BATCH 2
#define DH 32
#define RPB 8

typedef __attribute__((ext_vector_type(8))) short bshort8;
typedef __attribute__((ext_vector_type(4))) float f32x4;

// scale (Dh^-0.5) * log2(e), folded into q at projection time
#define QSCALE (0.17677669529663687f * 1.44269504f)

union U16B {
    uint4 u;
    bshort8 s8;
    __hip_bfloat16 h[8];
};

// ---------------- kernel 1: fused QKV projection (fp32 in -> bf16 q/k/vT) ---
// q prescaled by Dh^-0.5 * log2e. v written TRANSPOSED: vT[(b*8+h)*32+d][n]
__global__ __launch_bounds__(256) void qkv_kernel(
    const float* __restrict__ x,
    const float* __restrict__ Wqk,
    const float* __restrict__ Wv,
    __hip_bfloat16* __restrict__ q,
    __hip_bfloat16* __restrict__ k,
    __hip_bfloat16* __restrict__ vT) {
    __shared__ float xs[RPB][DIM];
    const int t = threadIdx.x;
    const int row0 = blockIdx.x * RPB;

#pragma unroll
    for (int j = 0; j < RPB; j++)
        xs[j][t] = x[(size_t)(row0 + j) * DIM + t];
    __syncthreads();

    float aq[RPB], ak[RPB], av[RPB];
#pragma unroll
    for (int j = 0; j < RPB; j++) { aq[j] = 0.f; ak[j] = 0.f; av[j] = 0.f; }

    for (int i = 0; i < DIM; i++) {
        float wq = Wqk[i * 512 + t];
        float wk = Wqk[i * 512 + 256 + t];
        float wv = Wv[i * 256 + t];
#pragma unroll
        for (int j = 0; j < RPB; j++) {
            float xv = xs[j][i];
            aq[j] = fmaf(xv, wq, aq[j]);
            ak[j] = fmaf(xv, wk, ak[j]);
            av[j] = fmaf(xv, wv, av[j]);
        }
    }

    const int h = t >> 5, d = t & 31;
    const int b = row0 >> 11, n0 = row0 & (NP - 1);
    U16B vv;
#pragma unroll
    for (int j = 0; j < RPB; j++) {
        size_t o = ((size_t)(b * NH + h) * NP + n0 + j) * DH + d;
        q[o] = __float2bfloat16(aq[j] * QSCALE);
        k[o] = __float2bfloat16(ak[j]);
        vv.h[j] = __float2bfloat16(av[j]);
    }
    // vT row = (b*8+h)*32 + d == b*256 + t ; cols n0..n0+7 (16B store)
    *(uint4*)(vT + ((size_t)(b * 256 + t)) * NP + n0) = vv.u;
}

// ---------------- kernel 2: MFMA flash-style gated positional attention -----
// grid: (b,h) x 32 q-blocks of 64. 4 waves, each owns 16 q rows.
__global__ __launch_bounds__(256, 2) void attn_kernel(
    const __hip_bfloat16* __restrict__ qg,
    const __hip_bfloat16* __restrict__ kg,
    const __hip_bfloat16* __restrict__ vTg,
    const float* __restrict__ Wpos,
    const float* __restrict__ bpos,
    const float* __restrict__ gating,
    float* __restrict__ attn_out) {
    __shared__ __hip_bfloat16 Kl[2][64][40];   // keys x dh (pad 32->40)
    __shared__ __hip_bfloat16 Vl[2][32][72];   // d x keys (pad 64->72)
    __shared__ __hip_bfloat16 Pl[4][2][16][72];// per-wave P (content,pos)

    const int t = threadIdx.x;
    const int lane = t & 63, wv = t >> 6;
    const int l15 = lane & 15, l4 = lane >> 4;
    const int bh = blockIdx.x >> 5;
    const int qb = blockIdx.x & 31;
    const int h = bh & (NH - 1);
    const int b = bh >> 3;
    const int q0 = qb * 64 + wv * 16;

    const float LOG2E = 1.44269504f;
    const float w0 = Wpos[h] * LOG2E;
    const float w1 = Wpos[NH + h] * LOG2E;
    const float bp = bpos[h] * LOG2E;
    const float g = 1.0f / (1.0f + __expf(-gating[h]));

    // Q A-fragment: A[m=l15][k=l4*8+j] (q prescaled by scale*log2e)
    U16B qv;
    qv.u = *(const uint4*)(qg + ((size_t)bh * NP + q0 + l15) * DH + l4 * 8);

    // analytic positional max per row (log2 units): max of p at m=0, m=n, m=N-1
    float nf[4], pmax[4];
#pragma unroll
    for (int r = 0; r < 4; r++) {
        nf[r] = (float)(q0 + l4 * 4 + r);
        float pm = fmaxf(bp, fmaf(w0 + w1, nf[r], bp));
        pmax[r] = fmaxf(pm, fmaf(w1 - w0, 2047.0f - nf[r], bp));
    }

    const __hip_bfloat16* ksrc = kg + (size_t)bh * NP * DH + (t >> 2) * DH + (t & 3) * 8;
    const __hip_bfloat16* vsrc = vTg + ((size_t)bh * DH + (t >> 3)) * NP + (t & 7) * 8;

    U16B kreg, vreg;
    kreg.u = *(const uint4*)ksrc;
    vreg.u = *(const uint4*)vsrc;
    *(uint4*)&Kl[0][t >> 2][(t & 3) * 8] = kreg.u;
    *(uint4*)&Vl[0][t >> 3][(t & 7) * 8] = vreg.u;
    __syncthreads();

    f32x4 o_s0 = {0.f, 0.f, 0.f, 0.f}, o_s1 = {0.f, 0.f, 0.f, 0.f};
    f32x4 o_p0 = {0.f, 0.f, 0.f, 0.f}, o_p1 = {0.f, 0.f, 0.f, 0.f};
    float ls[4] = {0.f, 0.f, 0.f, 0.f}, lp[4] = {0.f, 0.f, 0.f, 0.f};

    for (int it = 0; it < 32; ++it) {
        const int cur = it & 1;
        if (it < 31) {
            kreg.u = *(const uint4*)(ksrc + (size_t)(it + 1) * 64 * DH);
            vreg.u = *(const uint4*)(vsrc + (it + 1) * 64);
        }

        // S = Q @ K^T : 4 MFMAs (16q x 16k each, K=32)
        f32x4 s[4];
#pragma unroll
        for (int kt = 0; kt < 4; kt++) {
            bshort8 kf = *(const bshort8*)&Kl[cur][kt * 16 + l15][l4 * 8];
            s[kt] = __builtin_amdgcn_mfma_f32_16x16x32_bf16(
                qv.s8, kf, (f32x4){0.f, 0.f, 0.f, 0.f}, 0, 0, 0);
        }

        // exp (base-2, no max-sub for content; analytic max for positional)
        const float mkey0 = (float)(it * 64 + l15);
#pragma unroll
        for (int kt = 0; kt < 4; kt++) {
            float mk = mkey0 + (float)(kt * 16);
#pragma unroll
            for (int r = 0; r < 4; r++) {
                float es = exp2f(s[kt][r]);
                ls[r] += es;
                Pl[wv][0][l4 * 4 + r][kt * 16 + l15] = __float2bfloat16(es);
                float dd = nf[r] - mk;
                float p2 = fmaf(w1, fabsf(dd), fmaf(w0, dd, bp)) - pmax[r];
                float ep = exp2f(p2);
                lp[r] += ep;
                Pl[wv][1][l4 * 4 + r][kt * 16 + l15] = __float2bfloat16(ep);
            }
        }

        // O += P @ V (content and positional share V fragments)
#pragma unroll
        for (int ks = 0; ks < 2; ks++) {
            bshort8 pa = *(const bshort8*)&Pl[wv][0][l15][ks * 32 + l4 * 8];
            bshort8 pb = *(const bshort8*)&Pl[wv][1][l15][ks * 32 + l4 * 8];
            bshort8 v0 = *(const bshort8*)&Vl[cur][l15][ks * 32 + l4 * 8];
            bshort8 v1 = *(const bshort8*)&Vl[cur][16 + l15][ks * 32 + l4 * 8];
            o_s0 = __builtin_amdgcn_mfma_f32_16x16x32_bf16(pa, v0, o_s0, 0, 0, 0);
            o_s1 = __builtin_amdgcn_mfma_f32_16x16x32_bf16(pa, v1, o_s1, 0, 0, 0);
            o_p0 = __builtin_amdgcn_mfma_f32_16x16x32_bf16(pb, v0, o_p0, 0, 0, 0);
            o_p1 = __builtin_amdgcn_mfma_f32_16x16x32_bf16(pb, v1, o_p1, 0, 0, 0);
        }

        if (it < 31) {
            *(uint4*)&Kl[cur ^ 1][t >> 2][(t & 3) * 8] = kreg.u;
            *(uint4*)&Vl[cur ^ 1][t >> 3][(t & 7) * 8] = vreg.u;
        }
        __syncthreads();
    }

    // reduce row sums across the 16-lane column group (once, at the end)
#pragma unroll
    for (int r = 0; r < 4; r++) {
        float a = ls[r], c = lp[r];
        a += __shfl_xor(a, 1, 64); c += __shfl_xor(c, 1, 64);
        a += __shfl_xor(a, 2, 64); c += __shfl_xor(c, 2, 64);
        a += __shfl_xor(a, 4, 64); c += __shfl_xor(c, 4, 64);
        a += __shfl_xor(a, 8, 64); c += __shfl_xor(c, 8, 64);
        ls[r] = a; lp[r] = c;
    }

    // epilogue: out = (1-g)/ls * O_s + g/lp * O_p ; C-layout rows=(l4*4+r), col=l15
    const size_t obase = ((size_t)b * NP + q0 + l4 * 4) * DIM + h * DH + l15;
#pragma unroll
    for (int r = 0; r < 4; r++) {
        float cs = (1.0f - g) / ls[r];
        float cp = g / lp[r];
        attn_out[obase + (size_t)r * DIM]      = cs * o_s0[r] + cp * o_p0[r];
        attn_out[obase + (size_t)r * DIM + 16] = cs * o_s1[r] + cp * o_p1[r];
    }
}

// ---------------- kernel 3: output projection + bias (fp32) ----------------
__global__ __launch_bounds__(256) void proj_kernel(
    const float* __restrict__ a,
    const float* __restrict__ W,
    const float* __restrict__ bias,
    float* __restrict__ out) {
    __shared__ float xs[RPB][DIM];
    const int t = threadIdx.x;
    const int row0 = blockIdx.x * RPB;

#pragma unroll
    for (int j = 0; j < RPB; j++)
        xs[j][t] = a[(size_t)(row0 + j) * DIM + t];
    __syncthreads();

    float acc[RPB];
    float bb = bias[t];
#pragma unroll
    for (int j = 0; j < RPB; j++) acc[j] = bb;

    for (int i = 0; i < DIM; i++) {
        float wv = W[i * DIM + t];
#pragma unroll
        for (int j = 0; j < RPB; j++)
            acc[j] = fmaf(xs[j][i], wv, acc[j]);
    }

#pragma unroll
    for (int j = 0; j < RPB; j++)
        out[(size_t)(row0 + j) * DIM + t] = acc[j];
}

extern "C" void kernel_launch(void* const* d_in, const int* in_sizes, int n_in,
                              void* d_out, int out_size, void* d_ws, size_t ws_size,
                              hipStream_t stream) {
    const float* x      = (const float*)d_in[0];
    const float* Wqk    = (const float*)d_in[1];
    const float* Wv     = (const float*)d_in[2];
    const float* Wproj  = (const float*)d_in[3];
    const float* bproj  = (const float*)d_in[4];
    const float* Wpos   = (const float*)d_in[5];
    const float* bpos   = (const float*)d_in[6];
    const float* gating = (const float*)d_in[7];
    float* out = (float*)d_out;

    const size_t nElem = (size_t)BATCH * NH * NP * DH;  // 1,048,576
    char* w = (char*)d_ws;
    __hip_bfloat16* q  = (__hip_bfloat16*)w;
    __hip_bfloat16* k  = q + nElem;
    __hip_bfloat16* vT = k + nElem;
    float* attn_out = (float*)(w + 3 * nElem * sizeof(__hip_bfloat16));  // +6 MB

    qkv_kernel<<<BATCH * NP / RPB, 256, 0, stream>>>(x, Wqk, Wv, q, k, vT);
    attn_kernel<<<BATCH * NH * (NP / 64), 256, 0, stream>>>(q, k, vT, Wpos, bpos, gating, attn_out);
    proj_kernel<<<BATCH * NP / RPB, 256, 0, stream>>>(attn_out, Wproj, bproj, out);
}

// Round 5
// 146.606 us; speedup vs baseline: 4.0252x; 1.1918x over previous
//
#include <hip/hip_runtime.h>
#include <hip/hip_bf16.h>

#define DIM 256
#define NP 2048
#define NH 8
#define BATCH 2
#define DH 32

typedef __attribute__((ext_vector_type(8))) short bshort8;
typedef __attribute__((ext_vector_type(4))) float f32x4;

#define LOG2E 1.44269504f
// (Dh^-0.5) * log2(e), folded into q at projection time
#define QSCALE (0.17677669529663687f * LOG2E)

union U16B { uint4 u; bshort8 s8; __hip_bfloat16 h[8]; };
union U8B  { uint2 u; __hip_bfloat16 h[4]; };

// v_exp_f32: computes 2^x natively
__device__ __forceinline__ float fexp2(float x) { return __builtin_amdgcn_exp2f(x); }

// pack two fp32 -> two bf16 (truncation) in one v_perm
__device__ __forceinline__ unsigned packbf(float hi, float lo) {
    return __builtin_amdgcn_perm(__float_as_uint(hi), __float_as_uint(lo), 0x07060302u);
}

// ============ kernel 1: QKV projection as MFMA GEMM =========================
// A = x [4096 x 256] fp32 (cast bf16), B = [Wqk | Wv] [256 x 768] fp32 (cast)
// grid (64 M-blocks, 12 N-blocks), 256 thr. Wave owns 64 tokens x 16 cols.
// Outputs: q (prescaled), k in [bh][n][dh] bf16; v transposed vT[(b*256+c)][n].
__global__ __launch_bounds__(256) void qkv_mfma(
    const float* __restrict__ x,
    const float* __restrict__ Wqk,
    const float* __restrict__ Wv,
    __hip_bfloat16* __restrict__ q,
    __hip_bfloat16* __restrict__ k,
    __hip_bfloat16* __restrict__ vT) {
    const int t = threadIdx.x, lane = t & 63, wvid = t >> 6;
    const int l15 = lane & 15, l4 = lane >> 4;
    const int m0 = blockIdx.x * 64;
    const int nbase = blockIdx.y * 64 + wvid * 16;   // wave-uniform col base
    const int nc = nbase + l15;                      // this lane's output col

    const float* Wsrc; int ldw, wcol;
    if (nbase < 512) { Wsrc = Wqk; ldw = 512; wcol = nc; }
    else             { Wsrc = Wv;  ldw = 256; wcol = nc - 512; }

    f32x4 acc[4] = {{0.f,0.f,0.f,0.f},{0.f,0.f,0.f,0.f},{0.f,0.f,0.f,0.f},{0.f,0.f,0.f,0.f}};

    for (int k0 = 0; k0 < 256; k0 += 32) {
        U16B bw;
#pragma unroll
        for (int j = 0; j < 8; j++)
            bw.h[j] = __float2bfloat16(Wsrc[(size_t)(k0 + l4 * 8 + j) * ldw + wcol]);
#pragma unroll
        for (int mt = 0; mt < 4; mt++) {
            const float* xr = x + (size_t)(m0 + mt * 16 + l15) * 256 + k0 + l4 * 8;
            float4 f0 = *(const float4*)xr;
            float4 f1 = *(const float4*)(xr + 4);
            U16B ax;
            ax.h[0] = __float2bfloat16(f0.x); ax.h[1] = __float2bfloat16(f0.y);
            ax.h[2] = __float2bfloat16(f0.z); ax.h[3] = __float2bfloat16(f0.w);
            ax.h[4] = __float2bfloat16(f1.x); ax.h[5] = __float2bfloat16(f1.y);
            ax.h[6] = __float2bfloat16(f1.z); ax.h[7] = __float2bfloat16(f1.w);
            acc[mt] = __builtin_amdgcn_mfma_f32_16x16x32_bf16(ax.s8, bw.s8, acc[mt], 0, 0, 0);
        }
    }

    // epilogue: D[row = token = l4*4+r][col = nc]
    if (nbase < 256) {           // q (scaled)
        const int h = nc >> 5, d = nc & 31;
#pragma unroll
        for (int mt = 0; mt < 4; mt++)
#pragma unroll
            for (int r = 0; r < 4; r++) {
                int tok = m0 + mt * 16 + l4 * 4 + r;
                int b = tok >> 11, n = tok & (NP - 1);
                q[((size_t)(b * NH + h) * NP + n) * DH + d] = __float2bfloat16(acc[mt][r] * QSCALE);
            }
    } else if (nbase < 512) {    // k
        const int c = nc - 256, h = c >> 5, d = c & 31;
#pragma unroll
        for (int mt = 0; mt < 4; mt++)
#pragma unroll
            for (int r = 0; r < 4; r++) {
                int tok = m0 + mt * 16 + l4 * 4 + r;
                int b = tok >> 11, n = tok & (NP - 1);
                k[((size_t)(b * NH + h) * NP + n) * DH + d] = __float2bfloat16(acc[mt][r]);
            }
    } else {                     // vT: row = b*256 + c, cols = 4 consecutive tokens (8B store)
        const int c = nc - 512;
        const int b = m0 >> 11;
#pragma unroll
        for (int mt = 0; mt < 4; mt++) {
            int tokn = (m0 & (NP - 1)) + mt * 16 + l4 * 4;
            U8B vv;
#pragma unroll
            for (int r = 0; r < 4; r++) vv.h[r] = __float2bfloat16(acc[mt][r]);
            *(uint2*)(vT + (size_t)(b * 256 + c) * NP + tokn) = vv.u;
        }
    }
}

// ============ kernel 2: MFMA gated positional attention (no barriers) =======
// grid 512 = (b,h) x 32 q-blocks of 64; 4 waves x 16 queries.
// S^T = K@Q^T  ->  per-wave LDS repack (XOR-swizzled)  ->  O^T = V^T @ P^T
__global__ __launch_bounds__(256) void attn_kernel(
    const __hip_bfloat16* __restrict__ qg,
    const __hip_bfloat16* __restrict__ kg,
    const __hip_bfloat16* __restrict__ vTg,
    const float* __restrict__ Wpos,
    const float* __restrict__ bpos,
    const float* __restrict__ gating,
    __hip_bfloat16* __restrict__ ao) {
    // flat LDS: [wave][buf][type][16 q][64 keys], 16B-granule XOR swizzle
    __shared__ __align__(16) __hip_bfloat16 PsF[4 * 2 * 2 * 16 * 64];

    const int t = threadIdx.x;
    const int lane = t & 63, wvid = t >> 6;
    const int l15 = lane & 15, l4 = lane >> 4;
    const int bh = blockIdx.x >> 5, qb = blockIdx.x & 31;
    const int h = bh & (NH - 1), b = bh >> 3;
    const int q0 = qb * 64 + wvid * 16;
    const int myq = q0 + l15;
    const int swz = (l15 & 7);

    const float w0 = Wpos[h] * LOG2E;
    const float w1 = Wpos[NH + h] * LOG2E;
    const float g = 1.0f / (1.0f + __expf(-gating[h]));
    const float nf = (float)myq;
    // analytic positional max (bias dropped - cancels in softmax)
    const float pmax = fmaxf(0.f, fmaxf((w0 + w1) * nf, (w1 - w0) * (2047.0f - nf)));
    const float npmax = -pmax;

    // Q as B-fragment: B[k=dh=l4*8+j][n=query=l15]
    U16B qv;
    qv.u = *(const uint4*)(qg + ((size_t)bh * NP + myq) * DH + l4 * 8);

    const __hip_bfloat16* kbase = kg + (size_t)bh * NP * DH;
    const __hip_bfloat16* vtb   = vTg + (size_t)bh * DH * NP;

    f32x4 os0 = {0.f,0.f,0.f,0.f}, os1 = {0.f,0.f,0.f,0.f};
    f32x4 op0 = {0.f,0.f,0.f,0.f}, op1 = {0.f,0.f,0.f,0.f};
    float ls = 0.f, lp = 0.f;

    // prefetch iter 0
    U16B kf[4], vf0[2], vf1[2];
#pragma unroll
    for (int kt = 0; kt < 4; kt++)
        kf[kt].u = *(const uint4*)(kbase + (size_t)(kt * 16 + l15) * DH + l4 * 8);
#pragma unroll
    for (int win = 0; win < 2; win++) {
        vf0[win].u = *(const uint4*)(vtb + (size_t)l15 * NP + win * 32 + l4 * 8);
        vf1[win].u = *(const uint4*)(vtb + (size_t)(16 + l15) * NP + win * 32 + l4 * 8);
    }

#pragma unroll 2
    for (int it = 0; it < 32; ++it) {
        const int k0 = it * 64;
        const int psw = wvid * 4096 + (it & 1) * 2048;

        // S^T: A=K (m=key), B=Q (n=query) -> D[key=l4*4+r][query=l15]
        f32x4 st[4];
#pragma unroll
        for (int kt = 0; kt < 4; kt++)
            st[kt] = __builtin_amdgcn_mfma_f32_16x16x32_bf16(
                kf[kt].s8, qv.s8, (f32x4){0.f,0.f,0.f,0.f}, 0, 0, 0);

        // prefetch next iter's K / V^T fragments (independent of LDS section)
        U16B kn[4], vn0[2], vn1[2];
#pragma unroll
        for (int kt = 0; kt < 4; kt++)
            kn[kt].u = *(const uint4*)(kbase + (size_t)(k0 + 64 + kt * 16 + l15) * DH + l4 * 8);
#pragma unroll
        for (int win = 0; win < 2; win++) {
            vn0[win].u = *(const uint4*)(vtb + (size_t)l15 * NP + k0 + 64 + win * 32 + l4 * 8);
            vn1[win].u = *(const uint4*)(vtb + (size_t)(16 + l15) * NP + k0 + 64 + win * 32 + l4 * 8);
        }

        // exp + positional + pack + swizzled LDS write (4 consecutive keys/lane)
#pragma unroll
        for (int kt = 0; kt < 4; kt++) {
            const float dd0 = nf - (float)(k0 + kt * 16 + l4 * 4);
            float es0 = fexp2(st[kt][0]), es1 = fexp2(st[kt][1]);
            float es2 = fexp2(st[kt][2]), es3 = fexp2(st[kt][3]);
            ls += (es0 + es1) + (es2 + es3);
            float ep0, ep1, ep2, ep3;
            {
                float d0 = dd0, d1 = dd0 - 1.f, d2 = dd0 - 2.f, d3 = dd0 - 3.f;
                ep0 = fexp2(fmaf(w1, fabsf(d0), fmaf(w0, d0, npmax)));
                ep1 = fexp2(fmaf(w1, fabsf(d1), fmaf(w0, d1, npmax)));
                ep2 = fexp2(fmaf(w1, fabsf(d2), fmaf(w0, d2, npmax)));
                ep3 = fexp2(fmaf(w1, fabsf(d3), fmaf(w0, d3, npmax)));
            }
            lp += (ep0 + ep1) + (ep2 + ep3);
            const int g8 = 2 * kt + (l4 >> 1);
            const int off = psw + l15 * 64 + (((g8 ^ swz) << 3) + ((l4 & 1) << 2));
            uint2 pc, pp;
            pc.x = packbf(es1, es0); pc.y = packbf(es3, es2);
            pp.x = packbf(ep1, ep0); pp.y = packbf(ep3, ep2);
            *(uint2*)&PsF[off] = pc;
            *(uint2*)&PsF[off + 1024] = pp;
        }

        __builtin_amdgcn_wave_barrier();
        __builtin_amdgcn_s_waitcnt(0xc07f);   // lgkmcnt(0), vmcnt untouched
        __builtin_amdgcn_wave_barrier();

        // O^T += V^T @ P^T  (A = V^T frag, B = P^T frag from swizzled LDS)
#pragma unroll
        for (int win = 0; win < 2; win++) {
            const int g8 = 4 * win + l4;
            const int roff = psw + l15 * 64 + ((g8 ^ swz) << 3);
            bshort8 pa = *(const bshort8*)&PsF[roff];
            bshort8 pb = *(const bshort8*)&PsF[roff + 1024];
            os0 = __builtin_amdgcn_mfma_f32_16x16x32_bf16(vf0[win].s8, pa, os0, 0, 0, 0);
            os1 = __builtin_amdgcn_mfma_f32_16x16x32_bf16(vf1[win].s8, pa, os1, 0, 0, 0);
            op0 = __builtin_amdgcn_mfma_f32_16x16x32_bf16(vf0[win].s8, pb, op0, 0, 0, 0);
            op1 = __builtin_amdgcn_mfma_f32_16x16x32_bf16(vf1[win].s8, pb, op1, 0, 0, 0);
        }

#pragma unroll
        for (int kt = 0; kt < 4; kt++) kf[kt] = kn[kt];
#pragma unroll
        for (int win = 0; win < 2; win++) { vf0[win] = vn0[win]; vf1[win] = vn1[win]; }
    }

    // full row sums: reduce across the 4 l4-groups (lanes l15+16k)
    ls += __shfl_xor(ls, 16, 64); ls += __shfl_xor(ls, 32, 64);
    lp += __shfl_xor(lp, 16, 64); lp += __shfl_xor(lp, 32, 64);
    const float cs = (1.0f - g) / ls;
    const float cp = g / lp;

    // O^T: D[row=d=l4*4+r][col=query=l15] -> ao[token][h*32+d], bf16 8B stores
    const size_t orow = ((size_t)b * NP + q0 + l15) * DIM + h * DH;
    U8B o0, o1;
#pragma unroll
    for (int r = 0; r < 4; r++) {
        o0.h[r] = __float2bfloat16(cs * os0[r] + cp * op0[r]);
        o1.h[r] = __float2bfloat16(cs * os1[r] + cp * op1[r]);
    }
    *(uint2*)(ao + orow + l4 * 4)      = o0.u;
    *(uint2*)(ao + orow + 16 + l4 * 4) = o1.u;
}

// ============ kernel 3: output projection as MFMA GEMM ======================
// A = ao [4096 x 256] bf16, B = Wproj fp32 (cast), +bias, out fp32.
// grid (64, 4), 256 thr.
__global__ __launch_bounds__(256) void proj_mfma(
    const __hip_bfloat16* __restrict__ ao,
    const float* __restrict__ W,
    const float* __restrict__ bias,
    float* __restrict__ out) {
    const int t = threadIdx.x, lane = t & 63, wvid = t >> 6;
    const int l15 = lane & 15, l4 = lane >> 4;
    const int m0 = blockIdx.x * 64;
    const int nc = blockIdx.y * 64 + wvid * 16 + l15;

    f32x4 acc[4] = {{0.f,0.f,0.f,0.f},{0.f,0.f,0.f,0.f},{0.f,0.f,0.f,0.f},{0.f,0.f,0.f,0.f}};

    for (int k0 = 0; k0 < 256; k0 += 32) {
        U16B bw;
#pragma unroll
        for (int j = 0; j < 8; j++)
            bw.h[j] = __float2bfloat16(W[(size_t)(k0 + l4 * 8 + j) * 256 + nc]);
#pragma unroll
        for (int mt = 0; mt < 4; mt++) {
            U16B ax;
            ax.u = *(const uint4*)(ao + (size_t)(m0 + mt * 16 + l15) * 256 + k0 + l4 * 8);
            acc[mt] = __builtin_amdgcn_mfma_f32_16x16x32_bf16(ax.s8, bw.s8, acc[mt], 0, 0, 0);
        }
    }

    const float bb = bias[nc];
#pragma unroll
    for (int mt = 0; mt < 4; mt++)
#pragma unroll
        for (int r = 0; r < 4; r++) {
            int tok = m0 + mt * 16 + l4 * 4 + r;
            out[(size_t)tok * 256 + nc] = acc[mt][r] + bb;
        }
}

extern "C" void kernel_launch(void* const* d_in, const int* in_sizes, int n_in,
                              void* d_out, int out_size, void* d_ws, size_t ws_size,
                              hipStream_t stream) {
    const float* x      = (const float*)d_in[0];
    const float* Wqk    = (const float*)d_in[1];
    const float* Wv     = (const float*)d_in[2];
    const float* Wproj  = (const float*)d_in[3];
    const float* bproj  = (const float*)d_in[4];
    const float* Wpos   = (const float*)d_in[5];
    const float* bpos   = (const float*)d_in[6];
    const float* gating = (const float*)d_in[7];
    float* out = (float*)d_out;

    const size_t nElem = (size_t)BATCH * NH * NP * DH;  // 1,048,576
    char* w = (char*)d_ws;
    __hip_bfloat16* q  = (__hip_bfloat16*)w;
    __hip_bfloat16* k  = q + nElem;
    __hip_bfloat16* vT = k + nElem;
    __hip_bfloat16* ao = vT + nElem;   // bf16 attention output [4096][256]

    qkv_mfma<<<dim3(64, 12), 256, 0, stream>>>(x, Wqk, Wv, q, k, vT);
    attn_kernel<<<BATCH * NH * (NP / 64), 256, 0, stream>>>(q, k, vT, Wpos, bpos, gating, ao);
    proj_mfma<<<dim3(64, 4), 256, 0, stream>>>(ao, Wproj, bproj, out);
}